// Round 5
// baseline (436.975 us; speedup 1.0000x reference)
//
#include <hip/hip_runtime.h>
#include <stdint.h>

#define GRID_N (256*256*256)
#define MAXID 32
#define NCLS 13
#define NBINS ((MAXID+1)*NCLS)   // 429
#define PREP_BLOCKS 4096

// ws layout (bytes):
//   0     : int counts8[8][429]   (13728 B)
//   14336 : uint seen8[8]         (32 B)      -- both zeroed by 16384-B memset
//   16384 : int glut[34+35]       (key->pano lut 0..33, then sem_lut[35])
//   32768 : uint8 key[GRID_N]     (16 MiB: bits 0..5 = inst id / 32=wall / 33=floor,
//                                  bit 6 = surface (|geo|<=1.5))

__device__ __forceinline__ uint8_t keyb(int a, int b, float g) {
    int k = (b == 11) ? 33 : ((b == 10) ? 32 : a);
    return (uint8_t)(k | ((fabsf(g) <= 1.5f) ? 64 : 0));
}

// ---------------------------------------------------------------- pass 1
// Round-4 post-mortem: 82 us with ALL pipes idle across 3 structural
// variants => LDS-atomic lane throughput bound (~3 cyc/lane). Fix: only
// bins that are ever READ get atomics (id in ids2d+1 AND class not in
// {0,10,11} => ~31% of lanes); presence/zero_present via register
// seen-mask (no atomics).
__global__ __launch_bounds__(256) void k_prep(const float* __restrict__ geo,
                                              const int* __restrict__ inst,
                                              const int* __restrict__ sem,
                                              const int* __restrict__ ids2d, int n2d,
                                              int* __restrict__ counts8,
                                              unsigned int* __restrict__ seen8,
                                              uint8_t* __restrict__ key) {
    __shared__ int sh[4][NBINS];
    int t = threadIdx.x;
    for (int i = t; i < 4 * NBINS; i += 256) ((int*)sh)[i] = 0;
    __syncthreads();
    int* myh = sh[t >> 6];

    // bit j of m <=> id j is in (ids2d+1); uniform -> scalar loads
    uint64_t m = 0;
    for (int k = 0; k < n2d; ++k) m |= 1ull << (ids2d[k] + 1);

    unsigned int seen = 0;
    const int stride = PREP_BLOCKS * 256;
    const int4*   i4 = (const int4*)inst;
    const int4*   s4 = (const int4*)sem;
    const float4* g4 = (const float4*)geo;
    uchar4*       k4 = (uchar4*)key;

    int idx = blockIdx.x * 256 + t;
    #pragma unroll
    for (int it = 0; it < 4; ++it, idx += stride) {
        int4 a = i4[idx];
        int4 b = s4[idx];
        float4 g = g4[idx];
        uchar4 kk;
        kk.x = keyb(a.x, b.x, g.x);
        kk.y = keyb(a.y, b.y, g.y);
        kk.z = keyb(a.z, b.z, g.z);
        kk.w = keyb(a.w, b.w, g.w);
        k4[idx] = kk;
        seen |= (1u << a.x) | (1u << a.y) | (1u << a.z) | (1u << a.w);
        if (((m >> a.x) & 1) && b.x != 0 && b.x != 10 && b.x != 11)
            atomicAdd(&myh[a.x * NCLS + b.x], 1);
        if (((m >> a.y) & 1) && b.y != 0 && b.y != 10 && b.y != 11)
            atomicAdd(&myh[a.y * NCLS + b.y], 1);
        if (((m >> a.z) & 1) && b.z != 0 && b.z != 10 && b.z != 11)
            atomicAdd(&myh[a.z * NCLS + b.z], 1);
        if (((m >> a.w) & 1) && b.w != 0 && b.w != 10 && b.w != 11)
            atomicAdd(&myh[a.w * NCLS + b.w], 1);
    }

    // wave OR-reduce the seen mask, one atomicOr per wave (8-banked)
    #pragma unroll
    for (int o = 32; o; o >>= 1) seen |= (unsigned int)__shfl_xor((int)seen, o);
    if ((t & 63) == 0) atomicOr(&seen8[blockIdx.x & 7], seen);

    __syncthreads();
    int* dst = counts8 + (blockIdx.x & 7) * NBINS;
    for (int i = t; i < NBINS; i += 256) {
        int v = sh[0][i] + sh[1][i] + sh[2][i] + sh[3][i];
        if (v) atomicAdd(&dst[i], v);
    }
}

// ---------------------------------------------------------------- LUTs
__global__ __launch_bounds__(512) void k_luts(const int* __restrict__ counts8,
                                              const unsigned int* __restrict__ seen8,
                                              const int* __restrict__ ids2d, int n2d,
                                              int* __restrict__ glut) {
    __shared__ int shc[NBINS];
    __shared__ int sem_s[35];
    int t = threadIdx.x;
    if (t < NBINS) {
        int s = 0;
        #pragma unroll
        for (int c = 0; c < 8; ++c) s += counts8[c * NBINS + t];
        shc[t] = s;
    }
    __syncthreads();
    if (t < 64) {
        unsigned int seen = (t < 8) ? seen8[t] : 0u;
        #pragma unroll
        for (int o = 4; o; o >>= 1) seen |= (unsigned int)__shfl_xor((int)seen, o);
        seen = (unsigned int)__shfl((int)seen, 0);

        uint64_t m = 0;
        for (int k = 0; k < n2d; ++k) m |= 1ull << (ids2d[k] + 1);

        int in2d_t = (t <= MAXID) ? (int)((m >> t) & 1) : 0;
        int seen_t = (t < 32) ? (int)((seen >> t) & 1) : 0;
        int sel_t = 0;
        if (t <= MAXID) {
            int best = -2;
            for (int c = 0; c < NCLS; ++c) {
                int v = (c == 0 || c == 10 || c == 11) ? -1 : shc[t * NCLS + c];
                if (v > best) { best = v; sel_t = c; }
            }
        }
        // zero_present: any id 0..31 seen that is NOT in ids2d+1
        int zero_present = ((seen & ~(unsigned int)m) != 0u) ? 1 : 0;
        int pres = (t >= 1 && in2d_t && seen_t) ? 1 : 0;
        unsigned long long pm = __ballot(pres);
        int rank_below = __popcll(pm & ((1ULL << t) - 1ULL));
        int pano_id = pres ? (rank_below + zero_present + 2) : 0;

        if (t < 35) sem_s[t] = (t == 1) ? 10 : ((t == 2) ? 11 : 0);
        if (pres) sem_s[pano_id] = sel_t;   // disjoint ids; after defaults (same wave)

        if (t < 32) glut[t] = (t == 0) ? 0 : pano_id;   // key id -> pano id
        if (t == 32) glut[32] = 1;                      // wall
        if (t == 33) glut[33] = 2;                      // floor
        if (t < 35) glut[34 + t] = sem_s[t];            // sem_lut
    }
}

// ---------------------------------------------------------------- pass 2
// Tile = 8x8 (x,y) x full 256 z-line. LDS rows: 13x13 (x,y halo [-3,+2])
// x 264 bytes (z = -4..259 wrapped). Byte = grid0 | surface<<7.
#define TX 8
#define TY 8
#define HR 13              // TX+5
#define NROWS (HR*HR)      // 169
#define ROWDW 66           // 264 B per row
#define NDW (NROWS*ROWDW)  // 11154

__global__ __launch_bounds__(512) void k_nn(const uint8_t* __restrict__ key,
                                            const int* __restrict__ glut,
                                            int* __restrict__ out_pano,
                                            int* __restrict__ out_sem) {
    __shared__ uint32_t shg[NDW];     // 44616 B
    __shared__ int lut[128];          // key(7b incl surface) -> grid0 | surface<<7
    __shared__ int slut[MAXID + 3];

    int t = threadIdx.x;
    if (t < 128) {
        int base = ((t & 63) <= 33) ? glut[t & 63] : 0;
        lut[t] = base | ((t & 64) << 1);
    } else if (t >= 128 && t < 128 + MAXID + 3) {
        slut[t - 128] = glut[34 + (t - 128)];
    }
    __syncthreads();

    int x0 = blockIdx.x * TX;
    int y0 = blockIdx.y * TY;

    const uint32_t* key32 = (const uint32_t*)key;
    for (int idx = t; idx < NDW; idx += 512) {
        int row = idx / ROWDW;
        int k = idx - row * ROWDW;
        int ix = row / HR;
        int iy = row - ix * HR;
        int gx = (x0 + ix - 3) & 255;
        int gy = (y0 + iy - 3) & 255;
        uint32_t w = key32[(gx << 14) | (gy << 6) | ((k - 1) & 63)];
        shg[idx] = (uint32_t)lut[w & 127]
                 | ((uint32_t)lut[(w >> 8) & 127] << 8)
                 | ((uint32_t)lut[(w >> 16) & 127] << 16)
                 | ((uint32_t)lut[(w >> 24) & 127] << 24);
    }
    __syncthreads();

    int zg = t & 63;          // z-group: z = 4*zg .. 4*zg+3
    int ty = t >> 6;          // 0..7
    int gy = y0 + ty;
    const uint64_t M6 = 0x00007F7F7F7F7F7FULL;

    for (int x = 0; x < TX; ++x) {
        int gx = x0 + x;
        int r0 = (x + 3) * HR + (ty + 3);
        uint32_t cw = shg[r0 * ROWDW + zg + 1];   // 4 center bytes (z=4zg..+3)
        int4 pano, semv;
        int pv[4];
        #pragma unroll
        for (int b = 0; b < 4; ++b) {
            int v = (cw >> (8 * b)) & 255;
            int p = v & 127;
            if (p == 0 && (v & 128)) {
                int z = 4 * zg + b;
                int label = 0;
                int j0 = z + 1;
                int a0 = j0 >> 2, off = j0 & 3;
                for (int dxi = 0; dxi < 6 && !label; ++dxi) {
                    int rb = ((x + dxi) * HR + ty) * ROWDW + a0;
                    for (int dyi = 0; dyi < 6; ++dyi) {
                        int a = rb + dyi * ROWDW;
                        uint32_t d0 = shg[a], d1 = shg[a + 1], d2 = shg[a + 2];
                        uint64_t lo = (uint64_t)d0 | ((uint64_t)d1 << 32);
                        uint64_t win = lo >> (off * 8);
                        if (off) win |= (uint64_t)d2 << (64 - off * 8);
                        uint64_t mask = win & M6;   // 6 bytes, surface bit stripped
                        if (mask) {
                            int bb = __ffsll((long long)mask) - 1;
                            label = (int)((win >> (bb & 56)) & 0x7f);
                            break;
                        }
                    }
                }
                p = label;
            }
            pv[b] = p;
        }
        pano.x = pv[0]; pano.y = pv[1]; pano.z = pv[2]; pano.w = pv[3];
        semv.x = slut[pv[0]]; semv.y = slut[pv[1]]; semv.z = slut[pv[2]]; semv.w = slut[pv[3]];
        int oi = (gx << 14) | (gy << 6) | zg;     // int4 index
        ((int4*)out_pano)[oi] = pano;
        ((int4*)out_sem)[oi] = semv;
    }
}

extern "C" void kernel_launch(void* const* d_in, const int* in_sizes, int n_in,
                              void* d_out, int out_size, void* d_ws, size_t ws_size,
                              hipStream_t stream) {
    const float* geo   = (const float*)d_in[0];
    const int*   inst  = (const int*)d_in[1];
    const int*   sem   = (const int*)d_in[2];
    const int*   ids2d = (const int*)d_in[3];
    const int    n2d   = in_sizes[3];

    char* ws = (char*)d_ws;
    int* counts8          = (int*)(ws);
    unsigned int* seen8   = (unsigned int*)(ws + 14336);
    int* glut             = (int*)(ws + 16384);
    uint8_t* key          = (uint8_t*)(ws + 32768);

    int* out_pano = (int*)d_out;
    int* out_sem  = out_pano + GRID_N;

    hipMemsetAsync(counts8, 0, 16384, stream);
    k_prep<<<PREP_BLOCKS, 256, 0, stream>>>(geo, inst, sem, ids2d, n2d,
                                            counts8, seen8, key);
    k_luts<<<1, 512, 0, stream>>>(counts8, seen8, ids2d, n2d, glut);
    dim3 g(32, 32);
    k_nn<<<g, 512, 0, stream>>>(key, glut, out_pano, out_sem);
}

// Round 6
// 305.650 us; speedup vs baseline: 1.4297x; 1.4297x over previous
//
#include <hip/hip_runtime.h>
#include <stdint.h>

#define GRID_N (256*256*256)
#define MAXID 32
#define NCLS 13
#define NBINS ((MAXID+1)*NCLS)   // 429
#define PREP_BLOCKS 4096

// ws layout (bytes):
//   0     : int counts8[8][429]   (13728 B, zeroed via 16384-B memset)
//   16384 : uint seenArr[4096]    (16 KB, every entry written by its block -- no zeroing)
//   32768 : int glut[34+35]       (key->pano lut 0..33, then sem_lut[35])
//   49152 : uint8 key[GRID_N]     (16 MiB: bits 0..5 = inst id / 32=wall / 33=floor,
//                                  bit 6 = surface (|geo|<=1.5))

__device__ __forceinline__ uint8_t keyb(int a, int b, float g) {
    int k = (b == 11) ? 33 : ((b == 10) ? 32 : a);
    return (uint8_t)(k | ((fabsf(g) <= 1.5f) ? 64 : 0));
}

// ---------------------------------------------------------------- pass 1
// Round-5 post-mortem: the 213-us regression was the single-cache-line
// device-scope atomicOr (16384 atomics -> 1 line, cross-XCD serialization).
// Keep the GOOD part (conditional LDS atomics: conflicts 1.33M -> 564K) and
// replace the seen reduction with a plain per-block coalesced store.
__global__ __launch_bounds__(256) void k_prep(const float* __restrict__ geo,
                                              const int* __restrict__ inst,
                                              const int* __restrict__ sem,
                                              const int* __restrict__ ids2d, int n2d,
                                              int* __restrict__ counts8,
                                              unsigned int* __restrict__ seenArr,
                                              uint8_t* __restrict__ key) {
    __shared__ int sh[4][NBINS];
    __shared__ unsigned int wseen[4];
    int t = threadIdx.x;
    for (int i = t; i < 4 * NBINS; i += 256) ((int*)sh)[i] = 0;
    __syncthreads();
    int* myh = sh[t >> 6];

    // bit j of m <=> id j in (ids2d+1); eligC = classes not in {0,10,11}
    uint64_t m = 0;
    for (int k = 0; k < n2d; ++k) m |= 1ull << (ids2d[k] + 1);
    const unsigned int eligC = 0x13FE;

    unsigned int seen = 0;
    const int stride = PREP_BLOCKS * 256;
    const int4*   i4 = (const int4*)inst;
    const int4*   s4 = (const int4*)sem;
    const float4* g4 = (const float4*)geo;
    uchar4*       k4 = (uchar4*)key;

    int idx = blockIdx.x * 256 + t;
    #pragma unroll
    for (int it = 0; it < 4; ++it, idx += stride) {
        int4 a = i4[idx];
        int4 b = s4[idx];
        float4 g = g4[idx];
        uchar4 kk;
        kk.x = keyb(a.x, b.x, g.x);
        kk.y = keyb(a.y, b.y, g.y);
        kk.z = keyb(a.z, b.z, g.z);
        kk.w = keyb(a.w, b.w, g.w);
        k4[idx] = kk;
        seen |= (1u << a.x) | (1u << a.y) | (1u << a.z) | (1u << a.w);
        if (((unsigned)(m >> a.x) & (eligC >> b.x)) & 1)
            atomicAdd(&myh[a.x * NCLS + b.x], 1);
        if (((unsigned)(m >> a.y) & (eligC >> b.y)) & 1)
            atomicAdd(&myh[a.y * NCLS + b.y], 1);
        if (((unsigned)(m >> a.z) & (eligC >> b.z)) & 1)
            atomicAdd(&myh[a.z * NCLS + b.z], 1);
        if (((unsigned)(m >> a.w) & (eligC >> b.w)) & 1)
            atomicAdd(&myh[a.w * NCLS + b.w], 1);
    }

    // block seen mask: wave shfl-reduce -> LDS -> one plain store (NO atomics)
    #pragma unroll
    for (int o = 32; o; o >>= 1) seen |= (unsigned int)__shfl_xor((int)seen, o);
    if ((t & 63) == 0) wseen[t >> 6] = seen;
    __syncthreads();
    if (t == 0)
        seenArr[blockIdx.x] = wseen[0] | wseen[1] | wseen[2] | wseen[3];

    int* dst = counts8 + (blockIdx.x & 7) * NBINS;
    for (int i = t; i < NBINS; i += 256) {
        int v = sh[0][i] + sh[1][i] + sh[2][i] + sh[3][i];
        if (v) atomicAdd(&dst[i], v);
    }
}

// ---------------------------------------------------------------- LUTs
__global__ __launch_bounds__(512) void k_luts(const int* __restrict__ counts8,
                                              const unsigned int* __restrict__ seenArr,
                                              const int* __restrict__ ids2d, int n2d,
                                              int* __restrict__ glut) {
    __shared__ int shc[NBINS];
    __shared__ int sem_s[35];
    __shared__ unsigned int wseen[8];
    int t = threadIdx.x;

    // parallel OR-reduce of 4096 per-block seen masks
    unsigned int s = 0;
    #pragma unroll
    for (int i = 0; i < 8; ++i) s |= seenArr[t + i * 512];
    #pragma unroll
    for (int o = 32; o; o >>= 1) s |= (unsigned int)__shfl_xor((int)s, o);
    if ((t & 63) == 0) wseen[t >> 6] = s;

    if (t < NBINS) {
        int acc = 0;
        #pragma unroll
        for (int c = 0; c < 8; ++c) acc += counts8[c * NBINS + t];
        shc[t] = acc;
    }
    __syncthreads();
    if (t < 64) {
        unsigned int seen = wseen[0] | wseen[1] | wseen[2] | wseen[3]
                          | wseen[4] | wseen[5] | wseen[6] | wseen[7];
        uint64_t m = 0;
        for (int k = 0; k < n2d; ++k) m |= 1ull << (ids2d[k] + 1);

        int in2d_t = (t <= MAXID) ? (int)((m >> t) & 1) : 0;
        int seen_t = (t < 32) ? (int)((seen >> t) & 1) : 0;
        int sel_t = 0;
        if (t <= MAXID) {
            int best = -2;
            for (int c = 0; c < NCLS; ++c) {
                int v = (c == 0 || c == 10 || c == 11) ? -1 : shc[t * NCLS + c];
                if (v > best) { best = v; sel_t = c; }
            }
        }
        // zero_present: any id 0..31 seen that is NOT in ids2d+1
        int zero_present = ((seen & ~(unsigned int)m) != 0u) ? 1 : 0;
        int pres = (t >= 1 && in2d_t && seen_t) ? 1 : 0;
        unsigned long long pm = __ballot(pres);
        int rank_below = __popcll(pm & ((1ULL << t) - 1ULL));
        int pano_id = pres ? (rank_below + zero_present + 2) : 0;

        if (t < 35) sem_s[t] = (t == 1) ? 10 : ((t == 2) ? 11 : 0);
        if (pres) sem_s[pano_id] = sel_t;   // disjoint ids; after defaults (same wave)

        if (t < 32) glut[t] = (t == 0) ? 0 : pano_id;   // key id -> pano id
        if (t == 32) glut[32] = 1;                      // wall
        if (t == 33) glut[33] = 2;                      // floor
        if (t < 35) glut[34 + t] = sem_s[t];            // sem_lut
    }
}

// ---------------------------------------------------------------- pass 2
// Tile = 8x8 (x,y) x full 256 z-line. LDS rows: 13x13 (x,y halo [-3,+2])
// x 264 bytes (z = -4..259 wrapped). Byte = grid0 | surface<<7.
#define TX 8
#define TY 8
#define HR 13              // TX+5
#define NROWS (HR*HR)      // 169
#define ROWDW 66           // 264 B per row
#define NDW (NROWS*ROWDW)  // 11154

__global__ __launch_bounds__(512) void k_nn(const uint8_t* __restrict__ key,
                                            const int* __restrict__ glut,
                                            int* __restrict__ out_pano,
                                            int* __restrict__ out_sem) {
    __shared__ uint32_t shg[NDW];     // 44616 B
    __shared__ int lut[128];          // key(7b incl surface) -> grid0 | surface<<7
    __shared__ int slut[MAXID + 3];

    int t = threadIdx.x;
    if (t < 128) {
        int base = ((t & 63) <= 33) ? glut[t & 63] : 0;
        lut[t] = base | ((t & 64) << 1);
    } else if (t >= 128 && t < 128 + MAXID + 3) {
        slut[t - 128] = glut[34 + (t - 128)];
    }
    __syncthreads();

    int x0 = blockIdx.x * TX;
    int y0 = blockIdx.y * TY;

    const uint32_t* key32 = (const uint32_t*)key;
    for (int idx = t; idx < NDW; idx += 512) {
        int row = idx / ROWDW;
        int k = idx - row * ROWDW;
        int ix = row / HR;
        int iy = row - ix * HR;
        int gx = (x0 + ix - 3) & 255;
        int gy = (y0 + iy - 3) & 255;
        uint32_t w = key32[(gx << 14) | (gy << 6) | ((k - 1) & 63)];
        shg[idx] = (uint32_t)lut[w & 127]
                 | ((uint32_t)lut[(w >> 8) & 127] << 8)
                 | ((uint32_t)lut[(w >> 16) & 127] << 16)
                 | ((uint32_t)lut[(w >> 24) & 127] << 24);
    }
    __syncthreads();

    int zg = t & 63;          // z-group: z = 4*zg .. 4*zg+3
    int ty = t >> 6;          // 0..7
    int gy = y0 + ty;
    const uint64_t M6 = 0x00007F7F7F7F7F7FULL;

    for (int x = 0; x < TX; ++x) {
        int gx = x0 + x;
        int r0 = (x + 3) * HR + (ty + 3);
        uint32_t cw = shg[r0 * ROWDW + zg + 1];   // 4 center bytes (z=4zg..+3)
        int4 pano, semv;
        int pv[4];
        #pragma unroll
        for (int b = 0; b < 4; ++b) {
            int v = (cw >> (8 * b)) & 255;
            int p = v & 127;
            if (p == 0 && (v & 128)) {
                int z = 4 * zg + b;
                int label = 0;
                int j0 = z + 1;
                int a0 = j0 >> 2, off = j0 & 3;
                for (int dxi = 0; dxi < 6 && !label; ++dxi) {
                    int rb = ((x + dxi) * HR + ty) * ROWDW + a0;
                    for (int dyi = 0; dyi < 6; ++dyi) {
                        int a = rb + dyi * ROWDW;
                        uint32_t d0 = shg[a], d1 = shg[a + 1], d2 = shg[a + 2];
                        uint64_t lo = (uint64_t)d0 | ((uint64_t)d1 << 32);
                        uint64_t win = lo >> (off * 8);
                        if (off) win |= (uint64_t)d2 << (64 - off * 8);
                        uint64_t mask = win & M6;   // 6 bytes, surface bit stripped
                        if (mask) {
                            int bb = __ffsll((long long)mask) - 1;
                            label = (int)((win >> (bb & 56)) & 0x7f);
                            break;
                        }
                    }
                }
                p = label;
            }
            pv[b] = p;
        }
        pano.x = pv[0]; pano.y = pv[1]; pano.z = pv[2]; pano.w = pv[3];
        semv.x = slut[pv[0]]; semv.y = slut[pv[1]]; semv.z = slut[pv[2]]; semv.w = slut[pv[3]];
        int oi = (gx << 14) | (gy << 6) | zg;     // int4 index
        ((int4*)out_pano)[oi] = pano;
        ((int4*)out_sem)[oi] = semv;
    }
}

extern "C" void kernel_launch(void* const* d_in, const int* in_sizes, int n_in,
                              void* d_out, int out_size, void* d_ws, size_t ws_size,
                              hipStream_t stream) {
    const float* geo   = (const float*)d_in[0];
    const int*   inst  = (const int*)d_in[1];
    const int*   sem   = (const int*)d_in[2];
    const int*   ids2d = (const int*)d_in[3];
    const int    n2d   = in_sizes[3];

    char* ws = (char*)d_ws;
    int* counts8           = (int*)(ws);
    unsigned int* seenArr  = (unsigned int*)(ws + 16384);
    int* glut              = (int*)(ws + 32768);
    uint8_t* key           = (uint8_t*)(ws + 49152);

    int* out_pano = (int*)d_out;
    int* out_sem  = out_pano + GRID_N;

    hipMemsetAsync(counts8, 0, 16384, stream);
    k_prep<<<PREP_BLOCKS, 256, 0, stream>>>(geo, inst, sem, ids2d, n2d,
                                            counts8, seenArr, key);
    k_luts<<<1, 512, 0, stream>>>(counts8, seenArr, ids2d, n2d, glut);
    dim3 g(32, 32);
    k_nn<<<g, 512, 0, stream>>>(key, glut, out_pano, out_sem);
}